// Round 12
// baseline (123.447 us; speedup 1.0000x reference)
//
#include <hip/hip_runtime.h>

typedef _Float16 h4 __attribute__((ext_vector_type(4)));

static constexpr int IMG = 512;

__device__ __forceinline__ float gd_acc(float d, float acc) {
    const float t    = fmaf(d, d, 1.0f);
    const float rinv = __builtin_amdgcn_rcpf(t);
    const float e    = __builtin_amdgcn_exp2f(
                           -1.442695040888963f * __builtin_fabsf(d) * rinv);
    return fmaf(e, d, acc);
}

// One diffusion step, global->global, 4 px/thread, fp32 conv math.
// IN_HALF / OUT_HALF select _Float16 image I/O (intermediate steps).
template<bool IN_HALF, bool OUT_HALF>
__global__ __launch_bounds__(256) void ad_step(
    const void* __restrict__ inv, void* __restrict__ outv,
    const float* __restrict__ Wt, const float* __restrict__ bt)
{
    const int tid = threadIdx.x;
    const int x0  = blockIdx.x * 64 + (tid & 15) * 4;   // 0,4,...,508
    const int y   = blockIdx.y * 16 + (tid >> 4);       // 0..511

    float L[3][12];
    const bool xfast = (x0 >= 4) && (x0 <= 504);        // cols x0-4..x0+7 in-image

    if (IN_HALF) {
        const _Float16* __restrict__ src =
            (const _Float16*)inv + (size_t)blockIdx.z * (IMG * IMG);
#pragma unroll
        for (int dy = 0; dy < 3; ++dy) {
            const int yy = y + dy - 1;
            const bool rowok = (unsigned)yy < (unsigned)IMG;
            if (xfast && rowok) {
                const _Float16* p = src + yy * IMG + x0 - 4;  // 8B-aligned
                h4 a  = *(const h4*)(p);
                h4 bq = *(const h4*)(p + 4);
                h4 c  = *(const h4*)(p + 8);
#pragma unroll
                for (int j = 0; j < 4; ++j) {
                    L[dy][j]     = (float)a[j];
                    L[dy][j + 4] = (float)bq[j];
                    L[dy][j + 8] = (float)c[j];
                }
            } else {
#pragma unroll
                for (int j = 0; j < 12; ++j) {
                    const int col = x0 - 4 + j;
                    L[dy][j] = (rowok && (unsigned)col < (unsigned)IMG)
                                   ? (float)src[yy * IMG + col] : 0.f;
                }
            }
        }
    } else {
        const float* __restrict__ src =
            (const float*)inv + (size_t)blockIdx.z * (IMG * IMG);
#pragma unroll
        for (int dy = 0; dy < 3; ++dy) {
            const int yy = y + dy - 1;
            const bool rowok = (unsigned)yy < (unsigned)IMG;
            if (xfast && rowok) {
                const float* p = src + yy * IMG + x0 - 4;     // 16B-aligned
                *(float4*)&L[dy][0] = *(const float4*)(p);
                *(float4*)&L[dy][4] = *(const float4*)(p + 4);
                *(float4*)&L[dy][8] = *(const float4*)(p + 8);
            } else {
#pragma unroll
                for (int j = 0; j < 12; ++j) {
                    const int col = x0 - 4 + j;
                    L[dy][j] = (rowok && (unsigned)col < (unsigned)IMG)
                                   ? src[yy * IMG + col] : 0.f;
                }
            }
        }
    }

    float acc[4] = {0.f, 0.f, 0.f, 0.f};
#pragma unroll
    for (int k = 0; k < 8; ++k) {
        const float w0 = Wt[9*k+0], w1 = Wt[9*k+1], w2 = Wt[9*k+2];
        const float w3 = Wt[9*k+3], w4 = Wt[9*k+4], w5 = Wt[9*k+5];
        const float w6 = Wt[9*k+6], w7 = Wt[9*k+7], w8 = Wt[9*k+8];
        const float bk = bt[k];
#pragma unroll
        for (int i = 0; i < 4; ++i) {
            float d = bk;
            d = fmaf(w0, L[0][i+3], d);
            d = fmaf(w1, L[0][i+4], d);
            d = fmaf(w2, L[0][i+5], d);
            d = fmaf(w3, L[1][i+3], d);
            d = fmaf(w4, L[1][i+4], d);
            d = fmaf(w5, L[1][i+5], d);
            d = fmaf(w6, L[2][i+3], d);
            d = fmaf(w7, L[2][i+4], d);
            d = fmaf(w8, L[2][i+5], d);
            acc[i] = gd_acc(d, acc[i]);
        }
    }

    float v0 = L[1][4] - acc[0] * 0.125f;
    float v1 = L[1][5] - acc[1] * 0.125f;
    float v2 = L[1][6] - acc[2] * 0.125f;
    float v3 = L[1][7] - acc[3] * 0.125f;

    if (OUT_HALF) {
        _Float16* __restrict__ dst =
            (_Float16*)outv + (size_t)blockIdx.z * (IMG * IMG);
        h4 o;
        o[0] = (_Float16)v0; o[1] = (_Float16)v1;
        o[2] = (_Float16)v2; o[3] = (_Float16)v3;
        *(h4*)&dst[y * IMG + x0] = o;
    } else {
        float* __restrict__ dst =
            (float*)outv + (size_t)blockIdx.z * (IMG * IMG);
        float4 o = {v0, v1, v2, v3};
        *(float4*)&dst[y * IMG + x0] = o;
    }
}

// -------- Fallback: fused LDS kernel (only if ws too small) --------
static constexpr int TXF = 64;
static constexpr int TYF = 16;
static constexpr int LST = 72;
static constexpr int SROWS  = TYF + 6;
static constexpr int NSTAGE = SROWS * 18;

template<int WOFF, int NR, int RLO, int NG, bool TO_GLOBAL>
__device__ __forceinline__ void diffuse_step(
    const float* __restrict__ prev, float* __restrict__ cur,
    const float* __restrict__ Wt, const float* __restrict__ bt,
    int xoff, int ty0, int tx0, int tid, float* __restrict__ gout)
{
    constexpr int LOADW  = WOFF ? 8 : 6;
    constexpr int NITEMS = NR * NG;

    for (int idx = tid; idx < NITEMS; idx += 64) {
        const int rr = idx / NG, j = idx - rr * NG;
        const int r  = RLO + rr, c0 = 4 * j;
        const float* base = prev + (r - 1) * LST + c0;

        float L0[LOADW], L1[LOADW], L2[LOADW];
        *(float4*)&L0[0] = *(const float4*)(base);
        *(float4*)&L1[0] = *(const float4*)(base + LST);
        *(float4*)&L2[0] = *(const float4*)(base + 2 * LST);
        if (WOFF) {
            *(float4*)&L0[4] = *(const float4*)(base + 4);
            *(float4*)&L1[4] = *(const float4*)(base + LST + 4);
            *(float4*)&L2[4] = *(const float4*)(base + 2 * LST + 4);
        } else {
            *(float2*)&L0[4] = *(const float2*)(base + 4);
            *(float2*)&L1[4] = *(const float2*)(base + LST + 4);
            *(float2*)&L2[4] = *(const float2*)(base + 2 * LST + 4);
        }

        float acc[4] = {0.f, 0.f, 0.f, 0.f};
#pragma unroll
        for (int k = 0; k < 8; ++k) {
            const float w0 = Wt[9*k+0], w1 = Wt[9*k+1], w2 = Wt[9*k+2];
            const float w3 = Wt[9*k+3], w4 = Wt[9*k+4], w5 = Wt[9*k+5];
            const float w6 = Wt[9*k+6], w7 = Wt[9*k+7], w8 = Wt[9*k+8];
            const float bk = bt[k];
#pragma unroll
            for (int i = 0; i < 4; ++i) {
                float d = bk;
                d = fmaf(w0, L0[WOFF+i],   d);
                d = fmaf(w1, L0[WOFF+i+1], d);
                d = fmaf(w2, L0[WOFF+i+2], d);
                d = fmaf(w3, L1[WOFF+i],   d);
                d = fmaf(w4, L1[WOFF+i+1], d);
                d = fmaf(w5, L1[WOFF+i+2], d);
                d = fmaf(w6, L2[WOFF+i],   d);
                d = fmaf(w7, L2[WOFF+i+1], d);
                d = fmaf(w8, L2[WOFF+i+2], d);
                acc[i] = gd_acc(d, acc[i]);
            }
        }

        float4 v;
        v.x = L1[WOFF+1] - acc[0] * 0.125f;
        v.y = L1[WOFF+2] - acc[1] * 0.125f;
        v.z = L1[WOFF+3] - acc[2] * 0.125f;
        v.w = L1[WOFF+4] - acc[3] * 0.125f;

        const int gy = ty0 - 3 + r;
        if (TO_GLOBAL) {
            *(float4*)&gout[gy * IMG + tx0 + c0] = v;
        } else {
            const bool ry  = (unsigned)gy < (unsigned)IMG;
            const int  gx0 = xoff + c0;
            v.x = (ry && (unsigned)(gx0 + 0) < (unsigned)IMG) ? v.x : 0.f;
            v.y = (ry && (unsigned)(gx0 + 1) < (unsigned)IMG) ? v.y : 0.f;
            v.z = (ry && (unsigned)(gx0 + 2) < (unsigned)IMG) ? v.z : 0.f;
            v.w = (ry && (unsigned)(gx0 + 3) < (unsigned)IMG) ? v.w : 0.f;
            *(float4*)&cur[r * LST + c0] = v;
        }
    }
}

__global__ __launch_bounds__(64) void deep_ad_fused(
    const float* __restrict__ x, const float* __restrict__ W,
    const float* __restrict__ b, float* __restrict__ out)
{
    __shared__ float A[SROWS * LST];
    __shared__ float Bs[SROWS * LST];

    const int tid = threadIdx.x;
    const int tx0 = blockIdx.x * TXF;
    const int ty0 = blockIdx.y * TYF;
    const float* xin  = x   + (size_t)blockIdx.z * (IMG * IMG);
    float*       gout = out + (size_t)blockIdx.z * (IMG * IMG);

    {
        float4 sv[7];
#pragma unroll
        for (int q = 0; q < 7; ++q) {
            const int item = tid + 64 * q;
            const int rr = item / 18, j = item - rr * 18;
            const int gy = ty0 - 3 + rr;
            const int gx = tx0 - 4 + 4 * j;
            float4 v = {0.f, 0.f, 0.f, 0.f};
            if (item < NSTAGE && (unsigned)gy < (unsigned)IMG && (unsigned)gx < (unsigned)IMG)
                v = *(const float4*)(xin + gy * IMG + gx);
            sv[q] = v;
        }
#pragma unroll
        for (int q = 0; q < 7; ++q) {
            const int item = tid + 64 * q;
            if (item < NSTAGE) *(float4*)&A[item * 4] = sv[q];
        }
    }
    __syncthreads();

    diffuse_step<1, TYF + 4, 1, 17, false>(A,  Bs, W + 0,   b + 0,  tx0 - 2, ty0, tx0, tid, nullptr);
    __syncthreads();
    diffuse_step<0, TYF + 2, 2, 17, false>(Bs, A,  W + 72,  b + 8,  tx0 - 1, ty0, tx0, tid, nullptr);
    __syncthreads();
    diffuse_step<0, TYF,     3, 16, true >(A, nullptr, W + 144, b + 16, 0, ty0, tx0, tid, gout);
}

extern "C" void kernel_launch(void* const* d_in, const int* in_sizes, int n_in,
                              void* d_out, int out_size, void* d_ws, size_t ws_size,
                              hipStream_t stream)
{
    const float* x = (const float*)d_in[0];
    const float* W = (const float*)d_in[1];  // [3,8,1,3,3]
    const float* b = (const float*)d_in[2];  // [3,8]
    float* out = (float*)d_out;
    const int N = in_sizes[0] / (IMG * IMG); // 16

    const size_t halfImg = (size_t)N * IMG * IMG * sizeof(_Float16);  // 8.39 MB
    if (ws_size >= 2 * halfImg) {
        _Float16* buf1 = (_Float16*)d_ws;
        _Float16* buf2 = (_Float16*)((char*)d_ws + halfImg);
        dim3 g(IMG / 64, IMG / 16, N);                   // (8, 32, 16)
        ad_step<false, true ><<<g, 256, 0, stream>>>(x,    buf1, W + 0,   b + 0);
        ad_step<true,  true ><<<g, 256, 0, stream>>>(buf1, buf2, W + 72,  b + 8);
        ad_step<true,  false><<<g, 256, 0, stream>>>(buf2, out,  W + 144, b + 16);
    } else {
        dim3 grid(IMG / TXF, IMG / TYF, N);
        deep_ad_fused<<<grid, 64, 0, stream>>>(x, W, b, out);
    }
}